// Round 13
// baseline (176.854 us; speedup 1.0000x reference)
//
#include <hip/hip_runtime.h>
#include <stdint.h>

// Shapes (fixed by the reference)
#define B_  4096
#define V_  5
#define D_  512
#define NN_ (B_ * V_)            // 20480 text rows
#define NBLK_ 5120               // gemm grid 32 x 160

// p = exp((dot - 1)/T) = exp2(dot*C - C), C = log2(e)/T
#define C_EXP 20.609929155556620f   // 1.4426950408889634 / 0.07
#define M_SHIFT (1.0f / 0.07f)
#define SCALE1 0x7f7f7f7f           // e8m0 = 127 -> 2^0 in all 4 scale bytes

typedef float floatx4 __attribute__((ext_vector_type(4)));
typedef int   intx4   __attribute__((ext_vector_type(4)));
typedef int   intx8   __attribute__((ext_vector_type(8)));

// async global->LDS DMA, 16B per lane; LDS dest = wave-uniform base + lane*16
__device__ __forceinline__ void load_lds16(const void* g, void* l) {
  __builtin_amdgcn_global_load_lds(
      (const __attribute__((address_space(1))) unsigned int*)g,
      (__attribute__((address_space(3))) unsigned int*)l,
      16, 0, 0);
}

// ---------------------------------------------------------------------------
// Kernel 1: streaming fp32 -> fp8(e4m3) convert + accumulator zeroing.
// 3072 blocks x 256 threads x 16 floats = 12,582,912 exact. (unchanged r11)
// ---------------------------------------------------------------------------
__global__ void cvt_kernel(const float* __restrict__ img, const float* __restrict__ txt,
                           uint8_t* __restrict__ out8, float* __restrict__ acc) {
  const int t = blockIdx.x * 256 + threadIdx.x;     // 16-float group index
  if (t < B_ + NN_) acc[t] = 0.0f;                  // zero row/col sums
  const float4* src; int g;
  if (t < (B_ * D_) / 16) { src = (const float4*)img; g = t; }
  else                    { src = (const float4*)txt; g = t - (B_ * D_) / 16; }
  float4 a = src[4 * g + 0], b = src[4 * g + 1];
  float4 c = src[4 * g + 2], d = src[4 * g + 3];
  int w0 = __builtin_amdgcn_cvt_pk_fp8_f32(a.x, a.y, 0, 0);
  w0     = __builtin_amdgcn_cvt_pk_fp8_f32(a.z, a.w, w0, 1);
  int w1 = __builtin_amdgcn_cvt_pk_fp8_f32(b.x, b.y, 0, 0);
  w1     = __builtin_amdgcn_cvt_pk_fp8_f32(b.z, b.w, w1, 1);
  int w2 = __builtin_amdgcn_cvt_pk_fp8_f32(c.x, c.y, 0, 0);
  w2     = __builtin_amdgcn_cvt_pk_fp8_f32(c.z, c.w, w2, 1);
  int w3 = __builtin_amdgcn_cvt_pk_fp8_f32(d.x, d.y, 0, 0);
  w3     = __builtin_amdgcn_cvt_pk_fp8_f32(d.z, d.w, w3, 1);
  ((int4*)out8)[t] = make_int4(w0, w1, w2, w3);
}

// ---------------------------------------------------------------------------
// Kernel 2: fused MX-fp8 GEMM + exp + row/col sums + positives.
// CROSS-SUPERSTEP DOUBLE BUFFER: two 16KB superstep buffers per operand.
// At superstep ss: ONE barrier (drains DMAs issued a full superstep ago ->
// zero wait after fill), then issue ss+1's DMAs into the OTHER buffer (its
// readers finished in ss-1, guaranteed by this barrier) — barrier-B of r12
// eliminated, and the DMA in-flight window grows from ~550 to ~2900 cyc.
// 4 barriers/block total (r12: 8). LDS 64KB -> 2 blocks/CU.
// mfma_scale_f32_16x16x128_f8f6f4, unit scales; frag reads 2 x b128
// (conflict-free under the XOR swizzle); grid (32,160), m fastest.
// ---------------------------------------------------------------------------
__global__ __launch_bounds__(256, 2)
void gemm_kernel(const uint8_t* __restrict__ Ah, const uint8_t* __restrict__ Bh,
                 float* __restrict__ row_sum, float* __restrict__ col_sum,
                 float* __restrict__ posPart) {
  __shared__ __align__(16) uint8_t As[2][2 * 128 * 64];   // 2 ss-buffers x 16KB
  __shared__ __align__(16) uint8_t Bs[2][2 * 128 * 64];
  const int tid  = threadIdx.x;
  const int lane = tid & 63;
  const int w    = tid >> 6;                 // wave 0..3
  const int wm   = w >> 1, wn = w & 1;       // 2x2 wave grid
  const int m0   = blockIdx.x * 128;
  const int n0   = blockIdx.y * 128;

  floatx4 acc[4][4] = {};

  // --- staging (swizzled, r9-verified): lane L -> row L>>2, phys chunk L&3;
  // fetches global chunk (L&3)^((L>>3)&3), i.e. LDS(r,c)=global c^((r>>1)&3).
  const int sc = ((lane & 3) ^ ((lane >> 3) & 3)) * 16;    // bytes
  const uint8_t* gA = Ah + (size_t)(m0 + w * 32 + (lane >> 2)) * D_ + sc;
  const uint8_t* gB = Bh + (size_t)(n0 + w * 32 + (lane >> 2)) * D_ + sc;
  const int lofs = (w * 32) * 64;            // wave-uniform LDS offset (bytes)

  // --- fragment addressing (unchanged from r12) ---
  const int fr  = lane & 15;                 // frag m/n index
  const int swz = (fr >> 1) & 3;
  const int qb  = (lane >> 5) & 1;           // K-tile select within superstep
  const int qh  = (lane >> 4) & 1;           // 32B half within 64B row
  const int c0  = ((qh * 2 + 0) ^ swz) * 16; // phys chunk offsets (bytes)
  const int c1  = ((qh * 2 + 1) ^ swz) * 16;
  const int bufo = qb * 8192;                // second K-tile at +8KB

  // stage superstep s (K-tiles 2s, 2s+1) into buffers A/B
  #define STAGE(s, A, B) do {                                      \
    const int kg = (s) * 128;                                      \
    load_lds16(gA + kg,                (A) + lofs);                \
    load_lds16(gA + kg + 16 * D_,      (A) + lofs + 16 * 64);      \
    load_lds16(gB + kg,                (B) + lofs);                \
    load_lds16(gB + kg + 16 * D_,      (B) + lofs + 16 * 64);      \
    load_lds16(gA + kg + 64,           (A) + 8192 + lofs);         \
    load_lds16(gA + kg + 64 + 16 * D_, (A) + 8192 + lofs + 16 * 64); \
    load_lds16(gB + kg + 64,           (B) + 8192 + lofs);         \
    load_lds16(gB + kg + 64 + 16 * D_, (B) + 8192 + lofs + 16 * 64); \
  } while (0)

  STAGE(0, As[0], Bs[0]);                    // prologue: fill buffer 0

  for (int ss = 0; ss < 4; ++ss) {           // 4 supersteps x 128 K = 512
    const int p = ss & 1;
    __syncthreads();   // drains DMAs for buf p (issued one full superstep ago)

    if (ss < 3) STAGE(ss + 1, As[1 - p], Bs[1 - p]);   // prefetch next ss

    intx8 af[4], bf[4];
#pragma unroll
    for (int f = 0; f < 4; ++f) {
      const uint8_t* Ar = As[p] + bufo + (wm * 64 + f * 16 + fr) * 64;
      const uint8_t* Br = Bs[p] + bufo + (wn * 64 + f * 16 + fr) * 64;
      intx4 alo = *(const intx4*)(Ar + c0);
      intx4 ahi = *(const intx4*)(Ar + c1);
      intx4 blo = *(const intx4*)(Br + c0);
      intx4 bhi = *(const intx4*)(Br + c1);
      af[f] = __builtin_shufflevector(alo, ahi, 0, 1, 2, 3, 4, 5, 6, 7);
      bf[f] = __builtin_shufflevector(blo, bhi, 0, 1, 2, 3, 4, 5, 6, 7);
    }

#pragma unroll
    for (int mf = 0; mf < 4; ++mf)
#pragma unroll
      for (int nf = 0; nf < 4; ++nf)
        acc[mf][nf] = __builtin_amdgcn_mfma_scale_f32_16x16x128_f8f6f4(
            af[mf], bf[nf], acc[mf][nf],
            0, 0,                 // cbsz=FP8(e4m3), blgp=FP8(e4m3)
            0, SCALE1,            // opsel_a, scale_a = 1.0
            0, SCALE1);           // opsel_b, scale_b = 1.0
  }
  #undef STAGE

  // --- positive extraction from RAW acc (pre-exp): row == col/5 ---
  {
    float ps = 0.0f;
    const int iLo = n0 / 5, iHi = (n0 + 127) / 5;
    if (iHi >= m0 && iLo < m0 + 128) {       // block-uniform skip (~4/5 skip)
      const int rbase = m0 + wm * 64 + ((lane >> 4) << 2);
#pragma unroll
      for (int nf = 0; nf < 4; ++nf) {
        const int ci = (n0 + wn * 64 + nf * 16 + (lane & 15)) / 5;
#pragma unroll
        for (int mf = 0; mf < 4; ++mf)
#pragma unroll
          for (int r = 0; r < 4; ++r)
            if (rbase + mf * 16 + r == ci) ps += acc[mf][nf][r];
      }
    }
    for (int o = 32; o; o >>= 1) ps += __shfl_xor(ps, o);
    __shared__ float pls[4];
    if (lane == 0) pls[w] = ps;
    __syncthreads();
    if (tid == 0)
      posPart[blockIdx.y * 32 + blockIdx.x] = pls[0] + pls[1] + pls[2] + pls[3];
  }

  // Epilogue: p = exp2(dot*C - C); C/D layout: col=lane&15, row=(lane>>4)*4+reg
#pragma unroll
  for (int mf = 0; mf < 4; ++mf)
#pragma unroll
    for (int nf = 0; nf < 4; ++nf)
#pragma unroll
      for (int r = 0; r < 4; ++r)
        acc[mf][nf][r] = exp2f(acc[mf][nf][r] * C_EXP - C_EXP);

  // column sums over this wave's 64 rows
  float cs[4];
#pragma unroll
  for (int nf = 0; nf < 4; ++nf) {
    float s = 0.0f;
#pragma unroll
    for (int mf = 0; mf < 4; ++mf)
      s += acc[mf][nf][0] + acc[mf][nf][1] + acc[mf][nf][2] + acc[mf][nf][3];
    s += __shfl_xor(s, 16);
    s += __shfl_xor(s, 32);
    cs[nf] = s;
  }
  {
    int g = lane >> 4;                        // lane group g holds frag g's sums
    float v = (g == 0) ? cs[0] : (g == 1) ? cs[1] : (g == 2) ? cs[2] : cs[3];
    atomicAdd(&col_sum[n0 + wn * 64 + (g << 4) + (lane & 15)], v);
  }

  // row sums over this wave's 64 cols
#pragma unroll
  for (int mf = 0; mf < 4; ++mf) {
    floatx4 t = acc[mf][0] + acc[mf][1] + acc[mf][2] + acc[mf][3];
#pragma unroll
    for (int r = 0; r < 4; ++r) {
      float s = t[r];
      s += __shfl_xor(s, 1); s += __shfl_xor(s, 2);
      s += __shfl_xor(s, 4); s += __shfl_xor(s, 8);
      t[r] = s;
    }
    if ((lane & 15) < 4) {                    // 16 lanes cover 16 rows of this m-frag
      int q = lane & 3;
      float v = (q == 0) ? t[0] : (q == 1) ? t[1] : (q == 2) ? t[2] : t[3];
      atomicAdd(&row_sum[m0 + wm * 64 + mf * 16 + ((lane >> 4) << 2) + q], v);
    }
  }
}

// ---------------------------------------------------------------------------
// Kernel 3: loss = M + 0.5*(mean log rowsum + mean log colsum - 2*pos/(BV))
// ---------------------------------------------------------------------------
__global__ void finish_kernel(const float* __restrict__ acc, const float* __restrict__ posPart,
                              float* __restrict__ out) {
  int tid = threadIdx.x;                     // single block, 1024 threads
  float sA = 0.0f, sB = 0.0f, sP = 0.0f;
  for (int i = tid; i < B_;    i += 1024) sA += logf(acc[i]);
  for (int i = tid; i < NN_;   i += 1024) sB += logf(acc[B_ + i]);
  for (int i = tid; i < NBLK_; i += 1024) sP += posPart[i];
  float s = sA * (1.0f / B_) + sB * (1.0f / NN_)
          - sP * (2.0f * M_SHIFT / (float)NN_);
  for (int o = 32; o; o >>= 1) s += __shfl_xor(s, o);
  __shared__ float ls[16];
  int lane = tid & 63, w = tid >> 6;
  if (lane == 0) ls[w] = s;
  __syncthreads();
  if (tid == 0) {
    float tot = 0.0f;
#pragma unroll
    for (int i = 0; i < 16; ++i) tot += ls[i];
    out[0] = M_SHIFT + 0.5f * tot;
  }
}

// ---------------------------------------------------------------------------
extern "C" void kernel_launch(void* const* d_in, const int* in_sizes, int n_in,
                              void* d_out, int out_size, void* d_ws, size_t ws_size,
                              hipStream_t stream) {
  const float* img = (const float*)d_in[0];   // (4096, 512) fp32
  const float* txt = (const float*)d_in[1];   // (4096, 5, 512) fp32

  // workspace: [ img_fp8 | txt_fp8 | row_sum(B) col_sum(NN) posPart(NBLK) ]
  const size_t fp8Bytes = (size_t)(B_ * D_ + NN_ * D_);           // 12,582,912
  const size_t needBytes = fp8Bytes + (size_t)(B_ + NN_ + NBLK_) * 4;
  if (ws_size < needBytes) return;            // fail loudly (absmax), don't fault

  uint8_t* Ah  = (uint8_t*)d_ws;              // B*D bytes (txt follows contiguously)
  uint8_t* Bh  = Ah + (size_t)B_ * D_;        // NN*D bytes
  float* acc   = (float*)((char*)d_ws + fp8Bytes);
  float* row_s = acc;                         // [0, B_)
  float* col_s = acc + B_;                    // [B_, B_+NN_)
  float* posP  = acc + B_ + NN_;              // [B_+NN_, +NBLK_)

  cvt_kernel   <<<3072, 256, 0, stream>>>(img, txt, Ah, acc);
  gemm_kernel  <<<dim3(32, 160), 256, 0, stream>>>(Ah, Bh, row_s, col_s, posP);
  finish_kernel<<<1, 1024, 0, stream>>>(acc, posP, (float*)d_out);
}

// Round 14
// 157.097 us; speedup vs baseline: 1.1258x; 1.1258x over previous
//
#include <hip/hip_runtime.h>
#include <stdint.h>

// Shapes (fixed by the reference)
#define B_  4096
#define V_  5
#define D_  512
#define NN_ (B_ * V_)            // 20480 text rows
#define NBLK_ 5120               // gemm grid 32 x 160

// p = exp((dot - 1)/T) = exp2(dot*C - C), C = log2(e)/T
#define C_EXP 20.609929155556620f   // 1.4426950408889634 / 0.07
#define M_SHIFT (1.0f / 0.07f)
#define SCALE1 0x7f7f7f7f           // e8m0 = 127 -> 2^0 in all 4 scale bytes

typedef float floatx4 __attribute__((ext_vector_type(4)));
typedef int   intx4   __attribute__((ext_vector_type(4)));
typedef int   intx8   __attribute__((ext_vector_type(8)));

// async global->LDS DMA, 16B per lane; LDS dest = wave-uniform base + lane*16
__device__ __forceinline__ void load_lds16(const void* g, void* l) {
  __builtin_amdgcn_global_load_lds(
      (const __attribute__((address_space(1))) unsigned int*)g,
      (__attribute__((address_space(3))) unsigned int*)l,
      16, 0, 0);
}

// ---------------------------------------------------------------------------
// Kernel 1: streaming fp32 -> fp8(e4m3) convert + accumulator zeroing.
// 3072 blocks x 256 threads x 16 floats = 12,582,912 exact. (unchanged r11)
// ---------------------------------------------------------------------------
__global__ void cvt_kernel(const float* __restrict__ img, const float* __restrict__ txt,
                           uint8_t* __restrict__ out8, float* __restrict__ acc) {
  const int t = blockIdx.x * 256 + threadIdx.x;     // 16-float group index
  if (t < B_ + NN_) acc[t] = 0.0f;                  // zero row/col sums
  const float4* src; int g;
  if (t < (B_ * D_) / 16) { src = (const float4*)img; g = t; }
  else                    { src = (const float4*)txt; g = t - (B_ * D_) / 16; }
  float4 a = src[4 * g + 0], b = src[4 * g + 1];
  float4 c = src[4 * g + 2], d = src[4 * g + 3];
  int w0 = __builtin_amdgcn_cvt_pk_fp8_f32(a.x, a.y, 0, 0);
  w0     = __builtin_amdgcn_cvt_pk_fp8_f32(a.z, a.w, w0, 1);
  int w1 = __builtin_amdgcn_cvt_pk_fp8_f32(b.x, b.y, 0, 0);
  w1     = __builtin_amdgcn_cvt_pk_fp8_f32(b.z, b.w, w1, 1);
  int w2 = __builtin_amdgcn_cvt_pk_fp8_f32(c.x, c.y, 0, 0);
  w2     = __builtin_amdgcn_cvt_pk_fp8_f32(c.z, c.w, w2, 1);
  int w3 = __builtin_amdgcn_cvt_pk_fp8_f32(d.x, d.y, 0, 0);
  w3     = __builtin_amdgcn_cvt_pk_fp8_f32(d.z, d.w, w3, 1);
  ((int4*)out8)[t] = make_int4(w0, w1, w2, w3);
}

// ---------------------------------------------------------------------------
// Kernel 2: fused MX-fp8 GEMM + exp + row/col sums + positives.
// EXACT r12 structure (best: 86us): in-place 2-K-tile buffers, superstep =
// one K=128 MFMA step, barrier-A (vmcnt drain) + barrier-B (LDS RAW) per ss.
// r13 proved cross-ss dbuf loses: occupancy (2 blk/CU) + DMA-write/frag-read
// port contention outweigh the barrier savings. Changes vs r12:
//   * __launch_bounds__(256,4): LDS 32.5KB admits 4 blocks/CU; the 4th
//     co-resident block absorbs barrier drains (VGPR cap 128 >= 72, no spill).
//   * ss loop fully unrolled (compile-time DMA offsets).
// ---------------------------------------------------------------------------
__global__ __launch_bounds__(256, 4)
void gemm_kernel(const uint8_t* __restrict__ Ah, const uint8_t* __restrict__ Bh,
                 float* __restrict__ row_sum, float* __restrict__ col_sum,
                 float* __restrict__ posPart) {
  __shared__ __align__(16) uint8_t As[2 * 128 * 64];   // 16 KB (2 K-tiles)
  __shared__ __align__(16) uint8_t Bs[2 * 128 * 64];   // 16 KB
  const int tid  = threadIdx.x;
  const int lane = tid & 63;
  const int w    = tid >> 6;                 // wave 0..3
  const int wm   = w >> 1, wn = w & 1;       // 2x2 wave grid
  const int m0   = blockIdx.x * 128;
  const int n0   = blockIdx.y * 128;

  floatx4 acc[4][4] = {};

  // --- staging (swizzled, r9-verified): lane L -> row L>>2, phys chunk L&3;
  // fetches global chunk (L&3)^((L>>3)&3), i.e. LDS(r,c)=global c^((r>>1)&3).
  const int sc = ((lane & 3) ^ ((lane >> 3) & 3)) * 16;    // bytes
  const uint8_t* gA = Ah + (size_t)(m0 + w * 32 + (lane >> 2)) * D_ + sc;
  const uint8_t* gB = Bh + (size_t)(n0 + w * 32 + (lane >> 2)) * D_ + sc;
  const int lofs = (w * 32) * 64;            // wave-uniform LDS offset (bytes)

  // --- fragment addressing ---
  const int fr  = lane & 15;                 // frag m/n index
  const int swz = (fr >> 1) & 3;
  const int qb  = (lane >> 5) & 1;           // K-tile (buffer) select
  const int qh  = (lane >> 4) & 1;           // 32B half within 64B row
  const int c0  = ((qh * 2 + 0) ^ swz) * 16; // phys chunk offsets (bytes)
  const int c1  = ((qh * 2 + 1) ^ swz) * 16;
  const int bufo = qb * 8192;                // second K-tile at +8KB

  // stage K-tiles 2s, 2s+1 (tile t at global byte offset t*64)
  #define STAGE(s) do {                                            \
    const int kg = (s) * 128;                                      \
    load_lds16(gA + kg,                As + lofs);                 \
    load_lds16(gA + kg + 16 * D_,      As + lofs + 16 * 64);       \
    load_lds16(gB + kg,                Bs + lofs);                 \
    load_lds16(gB + kg + 16 * D_,      Bs + lofs + 16 * 64);       \
    load_lds16(gA + kg + 64,           As + 8192 + lofs);          \
    load_lds16(gA + kg + 64 + 16 * D_, As + 8192 + lofs + 16 * 64);\
    load_lds16(gB + kg + 64,           Bs + 8192 + lofs);          \
    load_lds16(gB + kg + 64 + 16 * D_, Bs + 8192 + lofs + 16 * 64);\
  } while (0)

  STAGE(0);                                  // prologue: fill both K-tiles

#pragma unroll
  for (int ss = 0; ss < 4; ++ss) {           // 4 supersteps x 128 K = 512
    __syncthreads();   // barrier A: drains the DMAs staged last superstep

    intx8 af[4], bf[4];
#pragma unroll
    for (int f = 0; f < 4; ++f) {
      const uint8_t* Ar = As + bufo + (wm * 64 + f * 16 + fr) * 64;
      const uint8_t* Br = Bs + bufo + (wn * 64 + f * 16 + fr) * 64;
      intx4 alo = *(const intx4*)(Ar + c0);
      intx4 ahi = *(const intx4*)(Ar + c1);
      intx4 blo = *(const intx4*)(Br + c0);
      intx4 bhi = *(const intx4*)(Br + c1);
      af[f] = __builtin_shufflevector(alo, ahi, 0, 1, 2, 3, 4, 5, 6, 7);
      bf[f] = __builtin_shufflevector(blo, bhi, 0, 1, 2, 3, 4, 5, 6, 7);
    }

    __syncthreads();   // barrier B: all reads done before in-place overwrite

    if (ss < 3) STAGE(ss + 1);               // stage next ss (overlaps MFMAs)

#pragma unroll
    for (int mf = 0; mf < 4; ++mf)
#pragma unroll
      for (int nf = 0; nf < 4; ++nf)
        acc[mf][nf] = __builtin_amdgcn_mfma_scale_f32_16x16x128_f8f6f4(
            af[mf], bf[nf], acc[mf][nf],
            0, 0,                 // cbsz=FP8(e4m3), blgp=FP8(e4m3)
            0, SCALE1,            // opsel_a, scale_a = 1.0
            0, SCALE1);           // opsel_b, scale_b = 1.0
  }
  #undef STAGE

  // --- positive extraction from RAW acc (pre-exp): row == col/5 ---
  {
    float ps = 0.0f;
    const int iLo = n0 / 5, iHi = (n0 + 127) / 5;
    if (iHi >= m0 && iLo < m0 + 128) {       // block-uniform skip (~4/5 skip)
      const int rbase = m0 + wm * 64 + ((lane >> 4) << 2);
#pragma unroll
      for (int nf = 0; nf < 4; ++nf) {
        const int ci = (n0 + wn * 64 + nf * 16 + (lane & 15)) / 5;
#pragma unroll
        for (int mf = 0; mf < 4; ++mf)
#pragma unroll
          for (int r = 0; r < 4; ++r)
            if (rbase + mf * 16 + r == ci) ps += acc[mf][nf][r];
      }
    }
    for (int o = 32; o; o >>= 1) ps += __shfl_xor(ps, o);
    __shared__ float pls[4];
    if (lane == 0) pls[w] = ps;
    __syncthreads();
    if (tid == 0)
      posPart[blockIdx.y * 32 + blockIdx.x] = pls[0] + pls[1] + pls[2] + pls[3];
  }

  // Epilogue: p = exp2(dot*C - C); C/D layout: col=lane&15, row=(lane>>4)*4+reg
#pragma unroll
  for (int mf = 0; mf < 4; ++mf)
#pragma unroll
    for (int nf = 0; nf < 4; ++nf)
#pragma unroll
      for (int r = 0; r < 4; ++r)
        acc[mf][nf][r] = exp2f(acc[mf][nf][r] * C_EXP - C_EXP);

  // column sums over this wave's 64 rows
  float cs[4];
#pragma unroll
  for (int nf = 0; nf < 4; ++nf) {
    float s = 0.0f;
#pragma unroll
    for (int mf = 0; mf < 4; ++mf)
      s += acc[mf][nf][0] + acc[mf][nf][1] + acc[mf][nf][2] + acc[mf][nf][3];
    s += __shfl_xor(s, 16);
    s += __shfl_xor(s, 32);
    cs[nf] = s;
  }
  {
    int g = lane >> 4;                        // lane group g holds frag g's sums
    float v = (g == 0) ? cs[0] : (g == 1) ? cs[1] : (g == 2) ? cs[2] : cs[3];
    atomicAdd(&col_sum[n0 + wn * 64 + (g << 4) + (lane & 15)], v);
  }

  // row sums over this wave's 64 cols
#pragma unroll
  for (int mf = 0; mf < 4; ++mf) {
    floatx4 t = acc[mf][0] + acc[mf][1] + acc[mf][2] + acc[mf][3];
#pragma unroll
    for (int r = 0; r < 4; ++r) {
      float s = t[r];
      s += __shfl_xor(s, 1); s += __shfl_xor(s, 2);
      s += __shfl_xor(s, 4); s += __shfl_xor(s, 8);
      t[r] = s;
    }
    if ((lane & 15) < 4) {                    // 16 lanes cover 16 rows of this m-frag
      int q = lane & 3;
      float v = (q == 0) ? t[0] : (q == 1) ? t[1] : (q == 2) ? t[2] : t[3];
      atomicAdd(&row_sum[m0 + wm * 64 + mf * 16 + ((lane >> 4) << 2) + q], v);
    }
  }
}

// ---------------------------------------------------------------------------
// Kernel 3: loss = M + 0.5*(mean log rowsum + mean log colsum - 2*pos/(BV))
// ---------------------------------------------------------------------------
__global__ void finish_kernel(const float* __restrict__ acc, const float* __restrict__ posPart,
                              float* __restrict__ out) {
  int tid = threadIdx.x;                     // single block, 1024 threads
  float sA = 0.0f, sB = 0.0f, sP = 0.0f;
  for (int i = tid; i < B_;    i += 1024) sA += logf(acc[i]);
  for (int i = tid; i < NN_;   i += 1024) sB += logf(acc[B_ + i]);
  for (int i = tid; i < NBLK_; i += 1024) sP += posPart[i];
  float s = sA * (1.0f / B_) + sB * (1.0f / NN_)
          - sP * (2.0f * M_SHIFT / (float)NN_);
  for (int o = 32; o; o >>= 1) s += __shfl_xor(s, o);
  __shared__ float ls[16];
  int lane = tid & 63, w = tid >> 6;
  if (lane == 0) ls[w] = s;
  __syncthreads();
  if (tid == 0) {
    float tot = 0.0f;
#pragma unroll
    for (int i = 0; i < 16; ++i) tot += ls[i];
    out[0] = M_SHIFT + 0.5f * tot;
  }
}

// ---------------------------------------------------------------------------
extern "C" void kernel_launch(void* const* d_in, const int* in_sizes, int n_in,
                              void* d_out, int out_size, void* d_ws, size_t ws_size,
                              hipStream_t stream) {
  const float* img = (const float*)d_in[0];   // (4096, 512) fp32
  const float* txt = (const float*)d_in[1];   // (4096, 5, 512) fp32

  // workspace: [ img_fp8 | txt_fp8 | row_sum(B) col_sum(NN) posPart(NBLK) ]
  const size_t fp8Bytes = (size_t)(B_ * D_ + NN_ * D_);           // 12,582,912
  const size_t needBytes = fp8Bytes + (size_t)(B_ + NN_ + NBLK_) * 4;
  if (ws_size < needBytes) return;            // fail loudly (absmax), don't fault

  uint8_t* Ah  = (uint8_t*)d_ws;              // B*D bytes (txt follows contiguously)
  uint8_t* Bh  = Ah + (size_t)B_ * D_;        // NN*D bytes
  float* acc   = (float*)((char*)d_ws + fp8Bytes);
  float* row_s = acc;                         // [0, B_)
  float* col_s = acc + B_;                    // [B_, B_+NN_)
  float* posP  = acc + B_ + NN_;              // [B_+NN_, +NBLK_)

  cvt_kernel   <<<3072, 256, 0, stream>>>(img, txt, Ah, acc);
  gemm_kernel  <<<dim3(32, 160), 256, 0, stream>>>(Ah, Bh, row_s, col_s, posP);
  finish_kernel<<<1, 1024, 0, stream>>>(acc, posP, (float*)d_out);
}

// Round 15
// 155.706 us; speedup vs baseline: 1.1358x; 1.0089x over previous
//
#include <hip/hip_runtime.h>
#include <stdint.h>

// Shapes (fixed by the reference)
#define B_  4096
#define V_  5
#define D_  512
#define NN_ (B_ * V_)            // 20480 text rows
#define NBLK_ 5120               // gemm grid 32 x 160
#define NIMG4_ ((B_ * D_) / 4)   // 524288 img float4 groups

// p = exp((dot - 1)/T) = exp2(dot*C - C), C = log2(e)/T
#define C_EXP 20.609929155556620f   // 1.4426950408889634 / 0.07
#define M_SHIFT (1.0f / 0.07f)
#define SCALE1 0x7f7f7f7f           // e8m0 = 127 -> 2^0 in all 4 scale bytes

typedef float floatx4 __attribute__((ext_vector_type(4)));
typedef int   intx4   __attribute__((ext_vector_type(4)));
typedef int   intx8   __attribute__((ext_vector_type(8)));

// async global->LDS DMA, 16B per lane; LDS dest = wave-uniform base + lane*16
__device__ __forceinline__ void load_lds16(const void* g, void* l) {
  __builtin_amdgcn_global_load_lds(
      (const __attribute__((address_space(1))) unsigned int*)g,
      (__attribute__((address_space(3))) unsigned int*)l,
      16, 0, 0);
}

// ---------------------------------------------------------------------------
// Kernel 1: fp32 -> fp8(e4m3) convert, FULLY COALESCED + accumulator zeroing.
// Session bug found in r14 post-mortem: every prior cvt had lanes at 64B
// stride within a load instruction (64 transactions/instr) -> r5 profile
// measured it at 455 GB/s / 137us. Now: thread t handles ONE float4 at a
// lane-consecutive index per grid-stride iter (4 x 786432 = 3,145,728 exact),
// stores one lane-consecutive uint (4 fp8 bytes). 1KB/wave coalesced loads.
// ---------------------------------------------------------------------------
__global__ void cvt_kernel(const float* __restrict__ img, const float* __restrict__ txt,
                           uint32_t* __restrict__ out32, float* __restrict__ acc) {
  const int tid0 = blockIdx.x * 256 + threadIdx.x;   // 0..786431
  if (tid0 < B_ + NN_) acc[tid0] = 0.0f;             // zero row/col sums
#pragma unroll
  for (int it = 0; it < 4; ++it) {
    const int idx = tid0 + it * (3072 * 256);        // float4 group index
    float4 v = (idx < NIMG4_) ? ((const float4*)img)[idx]
                              : ((const float4*)txt)[idx - NIMG4_];
    int w = __builtin_amdgcn_cvt_pk_fp8_f32(v.x, v.y, 0, 0);
    w     = __builtin_amdgcn_cvt_pk_fp8_f32(v.z, v.w, w, 1);
    out32[idx] = (uint32_t)w;
  }
}

// ---------------------------------------------------------------------------
// Kernel 2: fused MX-fp8 GEMM + exp + row/col sums + positives.
// UNCHANGED from r14 (best: 79.7us): in-place 2-K-tile buffers, superstep =
// one K=128 mfma_scale_f32_16x16x128_f8f6f4 step (unit scales), barrier-A
// (vmcnt drain) + barrier-B (LDS RAW) per ss, XOR bank swizzle,
// __launch_bounds__(256,4), fully unrolled ss loop, grid (32,160) m-fastest.
// ---------------------------------------------------------------------------
__global__ __launch_bounds__(256, 4)
void gemm_kernel(const uint8_t* __restrict__ Ah, const uint8_t* __restrict__ Bh,
                 float* __restrict__ row_sum, float* __restrict__ col_sum,
                 float* __restrict__ posPart) {
  __shared__ __align__(16) uint8_t As[2 * 128 * 64];   // 16 KB (2 K-tiles)
  __shared__ __align__(16) uint8_t Bs[2 * 128 * 64];   // 16 KB
  const int tid  = threadIdx.x;
  const int lane = tid & 63;
  const int w    = tid >> 6;                 // wave 0..3
  const int wm   = w >> 1, wn = w & 1;       // 2x2 wave grid
  const int m0   = blockIdx.x * 128;
  const int n0   = blockIdx.y * 128;

  floatx4 acc[4][4] = {};

  // --- staging (swizzled, r9-verified): lane L -> row L>>2, phys chunk L&3;
  // fetches global chunk (L&3)^((L>>3)&3), i.e. LDS(r,c)=global c^((r>>1)&3).
  const int sc = ((lane & 3) ^ ((lane >> 3) & 3)) * 16;    // bytes
  const uint8_t* gA = Ah + (size_t)(m0 + w * 32 + (lane >> 2)) * D_ + sc;
  const uint8_t* gB = Bh + (size_t)(n0 + w * 32 + (lane >> 2)) * D_ + sc;
  const int lofs = (w * 32) * 64;            // wave-uniform LDS offset (bytes)

  // --- fragment addressing ---
  const int fr  = lane & 15;                 // frag m/n index
  const int swz = (fr >> 1) & 3;
  const int qb  = (lane >> 5) & 1;           // K-tile (buffer) select
  const int qh  = (lane >> 4) & 1;           // 32B half within 64B row
  const int c0  = ((qh * 2 + 0) ^ swz) * 16; // phys chunk offsets (bytes)
  const int c1  = ((qh * 2 + 1) ^ swz) * 16;
  const int bufo = qb * 8192;                // second K-tile at +8KB

  // stage K-tiles 2s, 2s+1 (tile t at global byte offset t*64)
  #define STAGE(s) do {                                            \
    const int kg = (s) * 128;                                      \
    load_lds16(gA + kg,                As + lofs);                 \
    load_lds16(gA + kg + 16 * D_,      As + lofs + 16 * 64);       \
    load_lds16(gB + kg,                Bs + lofs);                 \
    load_lds16(gB + kg + 16 * D_,      Bs + lofs + 16 * 64);       \
    load_lds16(gA + kg + 64,           As + 8192 + lofs);          \
    load_lds16(gA + kg + 64 + 16 * D_, As + 8192 + lofs + 16 * 64);\
    load_lds16(gB + kg + 64,           Bs + 8192 + lofs);          \
    load_lds16(gB + kg + 64 + 16 * D_, Bs + 8192 + lofs + 16 * 64);\
  } while (0)

  STAGE(0);                                  // prologue: fill both K-tiles

#pragma unroll
  for (int ss = 0; ss < 4; ++ss) {           // 4 supersteps x 128 K = 512
    __syncthreads();   // barrier A: drains the DMAs staged last superstep

    intx8 af[4], bf[4];
#pragma unroll
    for (int f = 0; f < 4; ++f) {
      const uint8_t* Ar = As + bufo + (wm * 64 + f * 16 + fr) * 64;
      const uint8_t* Br = Bs + bufo + (wn * 64 + f * 16 + fr) * 64;
      intx4 alo = *(const intx4*)(Ar + c0);
      intx4 ahi = *(const intx4*)(Ar + c1);
      intx4 blo = *(const intx4*)(Br + c0);
      intx4 bhi = *(const intx4*)(Br + c1);
      af[f] = __builtin_shufflevector(alo, ahi, 0, 1, 2, 3, 4, 5, 6, 7);
      bf[f] = __builtin_shufflevector(blo, bhi, 0, 1, 2, 3, 4, 5, 6, 7);
    }

    __syncthreads();   // barrier B: all reads done before in-place overwrite

    if (ss < 3) STAGE(ss + 1);               // stage next ss (overlaps MFMAs)

#pragma unroll
    for (int mf = 0; mf < 4; ++mf)
#pragma unroll
      for (int nf = 0; nf < 4; ++nf)
        acc[mf][nf] = __builtin_amdgcn_mfma_scale_f32_16x16x128_f8f6f4(
            af[mf], bf[nf], acc[mf][nf],
            0, 0,                 // cbsz=FP8(e4m3), blgp=FP8(e4m3)
            0, SCALE1,            // opsel_a, scale_a = 1.0
            0, SCALE1);           // opsel_b, scale_b = 1.0
  }
  #undef STAGE

  // --- positive extraction from RAW acc (pre-exp): row == col/5 ---
  {
    float ps = 0.0f;
    const int iLo = n0 / 5, iHi = (n0 + 127) / 5;
    if (iHi >= m0 && iLo < m0 + 128) {       // block-uniform skip (~4/5 skip)
      const int rbase = m0 + wm * 64 + ((lane >> 4) << 2);
#pragma unroll
      for (int nf = 0; nf < 4; ++nf) {
        const int ci = (n0 + wn * 64 + nf * 16 + (lane & 15)) / 5;
#pragma unroll
        for (int mf = 0; mf < 4; ++mf)
#pragma unroll
          for (int r = 0; r < 4; ++r)
            if (rbase + mf * 16 + r == ci) ps += acc[mf][nf][r];
      }
    }
    for (int o = 32; o; o >>= 1) ps += __shfl_xor(ps, o);
    __shared__ float pls[4];
    if (lane == 0) pls[w] = ps;
    __syncthreads();
    if (tid == 0)
      posPart[blockIdx.y * 32 + blockIdx.x] = pls[0] + pls[1] + pls[2] + pls[3];
  }

  // Epilogue: p = exp2(dot*C - C); C/D layout: col=lane&15, row=(lane>>4)*4+reg
#pragma unroll
  for (int mf = 0; mf < 4; ++mf)
#pragma unroll
    for (int nf = 0; nf < 4; ++nf)
#pragma unroll
      for (int r = 0; r < 4; ++r)
        acc[mf][nf][r] = exp2f(acc[mf][nf][r] * C_EXP - C_EXP);

  // column sums over this wave's 64 rows
  float cs[4];
#pragma unroll
  for (int nf = 0; nf < 4; ++nf) {
    float s = 0.0f;
#pragma unroll
    for (int mf = 0; mf < 4; ++mf)
      s += acc[mf][nf][0] + acc[mf][nf][1] + acc[mf][nf][2] + acc[mf][nf][3];
    s += __shfl_xor(s, 16);
    s += __shfl_xor(s, 32);
    cs[nf] = s;
  }
  {
    int g = lane >> 4;                        // lane group g holds frag g's sums
    float v = (g == 0) ? cs[0] : (g == 1) ? cs[1] : (g == 2) ? cs[2] : cs[3];
    atomicAdd(&col_sum[n0 + wn * 64 + (g << 4) + (lane & 15)], v);
  }

  // row sums over this wave's 64 cols
#pragma unroll
  for (int mf = 0; mf < 4; ++mf) {
    floatx4 t = acc[mf][0] + acc[mf][1] + acc[mf][2] + acc[mf][3];
#pragma unroll
    for (int r = 0; r < 4; ++r) {
      float s = t[r];
      s += __shfl_xor(s, 1); s += __shfl_xor(s, 2);
      s += __shfl_xor(s, 4); s += __shfl_xor(s, 8);
      t[r] = s;
    }
    if ((lane & 15) < 4) {                    // 16 lanes cover 16 rows of this m-frag
      int q = lane & 3;
      float v = (q == 0) ? t[0] : (q == 1) ? t[1] : (q == 2) ? t[2] : t[3];
      atomicAdd(&row_sum[m0 + wm * 64 + mf * 16 + ((lane >> 4) << 2) + q], v);
    }
  }
}

// ---------------------------------------------------------------------------
// Kernel 3: loss = M + 0.5*(mean log rowsum + mean log colsum - 2*pos/(BV))
// ---------------------------------------------------------------------------
__global__ void finish_kernel(const float* __restrict__ acc, const float* __restrict__ posPart,
                              float* __restrict__ out) {
  int tid = threadIdx.x;                     // single block, 1024 threads
  float sA = 0.0f, sB = 0.0f, sP = 0.0f;
  for (int i = tid; i < B_;    i += 1024) sA += logf(acc[i]);
  for (int i = tid; i < NN_;   i += 1024) sB += logf(acc[B_ + i]);
  for (int i = tid; i < NBLK_; i += 1024) sP += posPart[i];
  float s = sA * (1.0f / B_) + sB * (1.0f / NN_)
          - sP * (2.0f * M_SHIFT / (float)NN_);
  for (int o = 32; o; o >>= 1) s += __shfl_xor(s, o);
  __shared__ float ls[16];
  int lane = tid & 63, w = tid >> 6;
  if (lane == 0) ls[w] = s;
  __syncthreads();
  if (tid == 0) {
    float tot = 0.0f;
#pragma unroll
    for (int i = 0; i < 16; ++i) tot += ls[i];
    out[0] = M_SHIFT + 0.5f * tot;
  }
}

// ---------------------------------------------------------------------------
extern "C" void kernel_launch(void* const* d_in, const int* in_sizes, int n_in,
                              void* d_out, int out_size, void* d_ws, size_t ws_size,
                              hipStream_t stream) {
  const float* img = (const float*)d_in[0];   // (4096, 512) fp32
  const float* txt = (const float*)d_in[1];   // (4096, 5, 512) fp32

  // workspace: [ img_fp8 | txt_fp8 | row_sum(B) col_sum(NN) posPart(NBLK) ]
  const size_t fp8Bytes = (size_t)(B_ * D_ + NN_ * D_);           // 12,582,912
  const size_t needBytes = fp8Bytes + (size_t)(B_ + NN_ + NBLK_) * 4;
  if (ws_size < needBytes) return;            // fail loudly (absmax), don't fault

  uint8_t* Ah  = (uint8_t*)d_ws;              // B*D bytes (txt follows contiguously)
  uint8_t* Bh  = Ah + (size_t)B_ * D_;        // NN*D bytes
  float* acc   = (float*)((char*)d_ws + fp8Bytes);
  float* row_s = acc;                         // [0, B_)
  float* col_s = acc + B_;                    // [B_, B_+NN_)
  float* posP  = acc + B_ + NN_;              // [B_+NN_, +NBLK_)

  cvt_kernel   <<<3072, 256, 0, stream>>>(img, txt, (uint32_t*)Ah, acc);
  gemm_kernel  <<<dim3(32, 160), 256, 0, stream>>>(Ah, Bh, row_s, col_s, posP);
  finish_kernel<<<1, 1024, 0, stream>>>(acc, posP, (float*)d_out);
}